// Round 19
// baseline (61.195 us; speedup 1.0000x reference)
//
#include <hip/hip_runtime.h>
#include <math.h>

#define K 2048           // time buckets
#define NHB 256          // histogram-role blocks, 1024 thr
#define NWB 256          // focal-role blocks, 1024 thr
#define NB (NHB + NWB)
#define PS_H 6144        // pw float4s per hist block
#define PS_W 10240       // pw float4s per focal block (256*(6144+10240) = nw/4)

// async global->LDS DMA: 64 lanes x 16 B = 1 KB per call, no VGPR destination.
// LDS dst = wave-uniform base + lane*16 (linear); global src is per-lane.
typedef const __attribute__((address_space(1))) void gas_t;
typedef __attribute__((address_space(3))) void las_t;
__device__ __forceinline__ void gld16(const void* g, void* s) {
    __builtin_amdgcn_global_load_lds((gas_t*)g, (las_t*)s, 16, 0, 0);
}

// ---------------- k1: DMA-staged, role-split, staggered ----------------------
__global__ __launch_bounds__(1024) void k1(
    const float* __restrict__ tm, const float* __restrict__ h,
    const int* __restrict__ ev,
    const float* __restrict__ rp, const int* __restrict__ rl,
    const float* __restrict__ pw,
    float* __restrict__ btot, unsigned* __restrict__ bev,
    double* __restrict__ partW, double* __restrict__ partH) {
    __shared__ __align__(16) char smem[49152];
    char*     stage  = smem;                      // 32 KB staging
    float*    hist   = (float*)(smem + 32768);    // [K] 8 KB
    unsigned* histev = (unsigned*)(smem + 40960); // [K] 8 KB
    double*   lred   = (double*)smem;             // reductions reuse stage

    int bid = blockIdx.x, tid = threadIdx.x;
    int lane = tid & 63, w = tid >> 6;            // 16 waves
    double foc = 0.0, reg = 0.0, seh = 0.0;
    int ne = 0;

#define SQ4(V) {                                                              \
        float s_ = (V).x * (V).x + (V).y * (V).y                              \
                 + (V).z * (V).z + (V).w * (V).w;                             \
        reg += (double)s_; }

    if (bid < NHB) {
        // ---- items: 8 chunks of 2048 (tm,h,ev via DMA) ----
        for (int j = tid; j < K; j += 1024) { hist[j] = 0.f; histev[j] = 0u; }
        const float* tmB = tm + (long long)bid * 16384;
        const float* hB  = h  + (long long)bid * 16384;
        const int*   evB = ev + (long long)bid * 16384;
        float2* tmS = (float2*)stage;              // 8 KB
        float2* hS  = (float2*)(stage + 8192);     // 8 KB
        int2*   evS = (int2*)(stage + 16384);      // 8 KB
#define HL(tc, hc, ec)                                                        \
        {                                                                     \
            unsigned b = (unsigned)((tc) * (float)K);                         \
            if (b > K - 1u) b = K - 1u;                                       \
            atomicAdd(&hist[b], __expf(hc));                                  \
            if (ec) { atomicAdd(&histev[b], 1u);                              \
                      seh += (double)(hc); ne += 1; }                         \
        }
        for (int c = 0; c < 8; ++c) {
            __syncthreads();                       // buffer reuse (+init) guard
            const float* tmC = tmB + c * 2048;
            const float* hC  = hB  + c * 2048;
            const int*   evC = evB + c * 2048;
            if (w < 8) {                           // waves 0-7: tm + ev calls
                gld16(tmC + w * 256 + lane * 4, stage + w * 1024);
                gld16(evC + w * 256 + lane * 4, stage + 16384 + w * 1024);
            } else {                               // waves 8-15: h calls
                int w8 = w - 8;
                gld16(hC + w8 * 256 + lane * 4, stage + 8192 + w8 * 1024);
            }
            __syncthreads();                       // drain DMA, publish chunk
            float2 t = tmS[tid];
            float2 hh = hS[tid];
            int2   e = evS[tid];
            HL(t.x, hh.x, e.x) HL(t.y, hh.y, e.y)
        }
#undef HL
        __syncthreads();
        for (int j = tid; j < K; j += 1024) {      // guarded flush
            float v = hist[j];
            if (v != 0.f) atomicAdd(&btot[j], v);
            unsigned c = histev[j];
            if (c) atomicAdd(&bev[j], c);
        }
        // ---- pw: 3 chunks of 2048 float4 (32 KB) ----
        const float4* pwB = (const float4*)pw + (long long)bid * PS_H;
        float4* pwS = (float4*)stage;
        for (int c = 0; c < 3; ++c) {
            __syncthreads();
            const float4* pwC = pwB + c * 2048;
            gld16(pwC + w * 64 + lane, stage + w * 1024);
            gld16(pwC + (w + 16) * 64 + lane, stage + (w + 16) * 1024);
            __syncthreads();
            float4 a = pwS[tid], b2 = pwS[tid + 1024];
            SQ4(a) SQ4(b2)
        }
    } else {
        int widx = bid - NHB;
        // ---- pw first: 5 chunks of 2048 float4 ----
        const float4* pwB = (const float4*)pw
                          + (long long)NHB * PS_H + (long long)widx * PS_W;
        float4* pwS = (float4*)stage;
        for (int c = 0; c < 5; ++c) {
            __syncthreads();
            const float4* pwC = pwB + c * 2048;
            gld16(pwC + w * 64 + lane, stage + w * 1024);
            gld16(pwC + (w + 16) * 64 + lane, stage + (w + 16) * 1024);
            __syncthreads();
            float4 a = pwS[tid], b2 = pwS[tid + 1024];
            SQ4(a) SQ4(b2)
        }
        // ---- items: 8 chunks of 2048 (rp,rl via DMA) ----
        const float* rpB = rp + (long long)widx * 16384;
        const int*   rlB = rl + (long long)widx * 16384;
        float2* rpS = (float2*)stage;
        int2*   rlS = (int2*)(stage + 8192);
#define FOC(pc, lc)                                                           \
        {                                                                     \
            float pp = pc; float tt = (float)(lc);                            \
            float ce = fmaxf(pp, 0.f) - pp * tt                               \
                     + __logf(1.f + __expf(-fabsf(pp)));                      \
            float ptv = __expf(-ce); float om = 1.f - ptv;                    \
            foc += (double)((0.25f * tt + 0.75f * (1.f - tt)) * om * om * ce);\
        }
        for (int c = 0; c < 8; ++c) {
            __syncthreads();
            const float* rpC = rpB + c * 2048;
            const int*   rlC = rlB + c * 2048;
            if (w < 8) {
                gld16(rpC + w * 256 + lane * 4, stage + w * 1024);
            } else {
                int w8 = w - 8;
                gld16(rlC + w8 * 256 + lane * 4, stage + 8192 + w8 * 1024);
            }
            __syncthreads();
            float2 p = rpS[tid];
            int2   l = rlS[tid];
            FOC(p.x, l.x) FOC(p.y, l.y)
        }
#undef FOC
    }
#undef SQ4

    // ---- block reductions (reuse stage as double[2048]) ----
    __syncthreads();
    lred[tid] = foc; lred[1024 + tid] = reg; __syncthreads();
    for (int s = 512; s > 0; s >>= 1) {
        if (tid < s) { lred[tid] += lred[tid + s]; lred[1024 + tid] += lred[1024 + tid + s]; }
        __syncthreads();
    }
    if (tid == 0) { partW[bid * 2 + 0] = lred[0]; partW[bid * 2 + 1] = lred[1024]; }
    if (bid < NHB) {
        __syncthreads();
        lred[tid] = seh; lred[1024 + tid] = (double)ne; __syncthreads();
        for (int s = 512; s > 0; s >>= 1) {
            if (tid < s) { lred[tid] += lred[tid + s]; lred[1024 + tid] += lred[1024 + tid + s]; }
            __syncthreads();
        }
        if (tid == 0) { partH[bid * 2 + 0] = lred[0]; partH[bid * 2 + 1] = lred[1024]; }
    }
}

// ---------------- kTail: pb + scan + dot + reduce + combine ------------------
__global__ __launch_bounds__(1024) void kTail(
    const float* __restrict__ btot, const unsigned* __restrict__ bev,
    const double* __restrict__ partW, const double* __restrict__ partH,
    const float* __restrict__ pb, int nb,
    const float* __restrict__ lsv, const float* __restrict__ lrv,
    const float* __restrict__ lgv, int n, float* __restrict__ out) {
    __shared__ double lds[2048];
    int tid = threadIdx.x;
    float v0 = btot[2 * tid], v1 = btot[2 * tid + 1];
    unsigned c0 = bev[2 * tid], c1 = bev[2 * tid + 1];
    lds[tid] = (double)v0 + (double)v1; __syncthreads();
    for (int off = 1; off < 1024; off <<= 1) {
        double a = (tid >= off) ? lds[tid - off] : 0.0;
        __syncthreads();
        lds[tid] += a;
        __syncthreads();
    }
    double run = (tid == 0) ? 0.0 : lds[tid - 1];
    double r0 = run + (double)v0;
    double r1 = r0 + (double)v1;
    double dot = 0.0;
    if (c0) dot += (double)c0 * log(r0);
    if (c1) dot += (double)c1 * log(r1);
    __syncthreads();

    double foc = 0.0, reg = 0.0, seh = 0.0, nev = 0.0;
    if (tid < NB)  { foc = partW[tid * 2 + 0]; reg = partW[tid * 2 + 1]; }
    if (tid < NHB) { seh = partH[tid * 2 + 0]; nev = partH[tid * 2 + 1]; }
    {
        int nb4 = nb >> 2;                         // pb: 1024 float4s
        if (tid < nb4) {
            float4 v = ((const float4*)pb)[tid];
            float s = v.x * v.x + v.y * v.y + v.z * v.z + v.w * v.w;
            reg += (double)s;
        }
    }

    lds[tid] = dot; lds[1024 + tid] = foc; __syncthreads();
    for (int s = 512; s > 0; s >>= 1) {
        if (tid < s) { lds[tid] += lds[tid + s]; lds[1024 + tid] += lds[1024 + tid + s]; }
        __syncthreads();
    }
    double dotT = lds[0], focT = lds[1024]; __syncthreads();
    lds[tid] = reg; lds[1024 + tid] = seh; __syncthreads();
    for (int s = 512; s > 0; s >>= 1) {
        if (tid < s) { lds[tid] += lds[tid + s]; lds[1024 + tid] += lds[1024 + tid + s]; }
        __syncthreads();
    }
    double regT = lds[0], sehT = lds[1024]; __syncthreads();
    lds[tid] = nev; __syncthreads();
    for (int s = 512; s > 0; s >>= 1) {
        if (tid < s) lds[tid] += lds[tid + s];
        __syncthreads();
    }
    if (tid == 0) {
        double neT = lds[0];
        double cox = sehT - dotT;                  // Σ_events (h - logS)
        double surv = -cox / (neT + 1e-8);
        double rec = focT / (double)n;
        double rg = 1e-4 * regT;
        double a = (double)lsv[0], b = (double)lrv[0], c = (double)lgv[0];
        double sp = exp(-a), rpv = exp(-b), gp = exp(-c);
        double total = sp * surv + rpv * rec + gp * rg + a + b + c;
        out[0] = (float)total;
        out[1] = (float)surv;
        out[2] = (float)rec;
        out[3] = (float)rg;
        out[4] = (float)sp;
        out[5] = (float)rpv;
    }
}

extern "C" void kernel_launch(void* const* d_in, const int* in_sizes, int n_in,
                              void* d_out, int out_size, void* d_ws, size_t ws_size,
                              hipStream_t stream) {
    const float* h   = (const float*)d_in[0];
    const float* rp  = (const float*)d_in[1];
    const float* tm  = (const float*)d_in[2];
    const int*   ev  = (const int*)d_in[3];
    const int*   rl  = (const int*)d_in[4];
    const float* pw  = (const float*)d_in[5];
    const float* pb  = (const float*)d_in[6];
    const float* lsv = (const float*)d_in[7];
    const float* lrv = (const float*)d_in[8];
    const float* lgv = (const float*)d_in[9];
    int n  = in_sizes[0];
    int nb = in_sizes[6];
    float* out = (float*)d_out;

    float*    btot  = (float*)d_ws;                // K floats
    unsigned* bev   = (unsigned*)(btot + K);       // K uints
    double*   partW = (double*)(bev + K);          // NB*2 doubles
    double*   partH = partW + 2 * NB;              // NHB*2 doubles

    hipMemsetAsync(btot, 0, (size_t)K * 8, stream);   // btot + bev
    k1<<<NB, 1024, 0, stream>>>(tm, h, ev, rp, rl, pw,
                                btot, bev, partW, partH);
    kTail<<<1, 1024, 0, stream>>>(btot, bev, partW, partH, pb, nb,
                                  lsv, lrv, lgv, n, out);
}

// Round 20
// 51.895 us; speedup vs baseline: 1.1792x; 1.1792x over previous
//
#include <hip/hip_runtime.h>
#include <math.h>

#define K 2048           // time buckets
#define NREP 8           // btot/bev replicas (atomic contention / 8)
#define NHB 256          // histogram-role blocks, 1024 thr
#define NWB 256          // focal-role blocks, 1024 thr
#define NB (NHB + NWB)
#define PS_H 6144        // pw float4s per hist block
#define PS_W 10240       // pw float4s per work block (256*(6144+10240) = nw/4)

// ---------------- k1: R10 structure + replicated rotated flush ---------------
__global__ __launch_bounds__(1024) void k1(
    const float* __restrict__ tm, const float* __restrict__ h,
    const int* __restrict__ ev, int n,
    const float* __restrict__ rp, const int* __restrict__ rl,
    const float* __restrict__ pw, int nw,
    const float* __restrict__ pb, int nb,
    float* __restrict__ btot, unsigned* __restrict__ bev,
    double* __restrict__ partW, double* __restrict__ partH) {
    __shared__ __align__(16) char smem[16384];
    float*    hist   = (float*)smem;              // [K]
    unsigned* histev = (unsigned*)(smem + 8192);  // [K]
    double*   lds    = (double*)smem;             // reused after flush
    int bid = blockIdx.x, tid = threadIdx.x;
    double foc = 0.0, reg = 0.0, seh = 0.0;
    int ne = 0;

    const float4* mypw;
    int mycnt;

    if (bid < NHB) {
        // ---- histogram role ----
        for (int j = tid; j < K; j += 1024) { hist[j] = 0.f; histev[j] = 0u; }
        __syncthreads();
        const float4* tm4 = (const float4*)tm + (long long)bid * 4096;
        const float4* h4  = (const float4*)h  + (long long)bid * 4096;
        const int4*   ev4 = (const int4*)ev  + (long long)bid * 4096;
#define HL(tc, hc, ec)                                                        \
        {                                                                     \
            unsigned b = (unsigned)((tc) * (float)K);                         \
            if (b > K - 1u) b = K - 1u;                                       \
            atomicAdd(&hist[b], __expf(hc));                                  \
            if (ec) { atomicAdd(&histev[b], 1u);                              \
                      seh += (double)(hc); ne += 1; }                         \
        }
        for (int i = tid; i < 4096; i += 2048) {   // 2 iters; 6 loads in flight
            float4 T0 = tm4[i],        H0 = h4[i];
            int4   E0 = ev4[i];
            float4 T1 = tm4[i + 1024], H1 = h4[i + 1024];
            int4   E1 = ev4[i + 1024];
            HL(T0.x, H0.x, E0.x) HL(T0.y, H0.y, E0.y)
            HL(T0.z, H0.z, E0.z) HL(T0.w, H0.w, E0.w)
            HL(T1.x, H1.x, E1.x) HL(T1.y, H1.y, E1.y)
            HL(T1.z, H1.z, E1.z) HL(T1.w, H1.w, E1.w)
        }
#undef HL
        __syncthreads();
        // ---- replicated + rotated flush: per-address queue depth /8 ----
        {
            float*    myb  = btot + (size_t)(bid & (NREP - 1)) * K;
            unsigned* mybe = bev  + (size_t)(bid & (NREP - 1)) * K;
            int rot = (bid * 37) & (K - 1);
            for (int jj = tid; jj < K; jj += 1024) {
                int j = (jj + rot) & (K - 1);
                float v = hist[j];
                if (v != 0.f) atomicAdd(&myb[j], v);
                unsigned c = histev[j];
                if (c) atomicAdd(&mybe[j], c);
            }
        }
        mypw  = (const float4*)pw + (long long)bid * PS_H;
        mycnt = PS_H;
    } else {
        // ---- focal role ----
        int widx = bid - NHB;
        const float4* rp4 = (const float4*)rp + (long long)widx * 4096;
        const int4*   rl4 = (const int4*)rl + (long long)widx * 4096;
#define FOC(pc, lc)                                                           \
        {                                                                     \
            float pp = pc; float tt = (float)(lc);                            \
            float ce = fmaxf(pp, 0.f) - pp * tt                               \
                     + __logf(1.f + __expf(-fabsf(pp)));                      \
            float ptv = __expf(-ce); float om = 1.f - ptv;                    \
            foc += (double)((0.25f * tt + 0.75f * (1.f - tt)) * om * om * ce);\
        }
        for (int i = tid; i < 4096; i += 2048) {   // 2 iters; 4 loads in flight
            float4 P0 = rp4[i];
            int4   L0 = rl4[i];
            float4 P1 = rp4[i + 1024];
            int4   L1 = rl4[i + 1024];
            FOC(P0.x, L0.x) FOC(P0.y, L0.y) FOC(P0.z, L0.z) FOC(P0.w, L0.w)
            FOC(P1.x, L1.x) FOC(P1.y, L1.y) FOC(P1.z, L1.z) FOC(P1.w, L1.w)
        }
#undef FOC
        mypw  = (const float4*)pw + (long long)NHB * PS_H + (long long)widx * PS_W;
        mycnt = PS_W;
    }

    // ---- common: pw slice ----
#define SQ4(V) {                                                              \
        float s_ = (V).x * (V).x + (V).y * (V).y                              \
                 + (V).z * (V).z + (V).w * (V).w;                             \
        reg += (double)s_; }
#pragma unroll 2
    for (int i = tid; i < mycnt; i += 1024) {
        float4 v = mypw[i];
        SQ4(v)
    }
    if (bid == NHB) {                              // pb: 1024 float4s, once
        int nb4 = nb >> 2;
        if (tid < nb4) {
            float4 v = ((const float4*)pb)[tid];
            SQ4(v)
        }
    }
#undef SQ4

    __syncthreads();                               // LDS hist no longer needed
    lds[tid] = foc; lds[1024 + tid] = reg; __syncthreads();
    for (int s = 512; s > 0; s >>= 1) {
        if (tid < s) { lds[tid] += lds[tid + s]; lds[1024 + tid] += lds[1024 + tid + s]; }
        __syncthreads();
    }
    if (tid == 0) { partW[bid * 2 + 0] = lds[0]; partW[bid * 2 + 1] = lds[1024]; }
    if (bid < NHB) {
        __syncthreads();
        lds[tid] = seh; lds[1024 + tid] = (double)ne; __syncthreads();
        for (int s = 512; s > 0; s >>= 1) {
            if (tid < s) { lds[tid] += lds[tid + s]; lds[1024 + tid] += lds[1024 + tid + s]; }
            __syncthreads();
        }
        if (tid == 0) { partH[bid * 2 + 0] = lds[0]; partH[bid * 2 + 1] = lds[1024]; }
    }
}

// ---------------- kTail: replica-sum + scan + dot + reduce + combine ---------
__global__ __launch_bounds__(1024) void kTail(
    const float* __restrict__ btot, const unsigned* __restrict__ bev,
    const double* __restrict__ partW, const double* __restrict__ partH,
    const float* __restrict__ lsv, const float* __restrict__ lrv,
    const float* __restrict__ lgv, int n, float* __restrict__ out) {
    __shared__ double lds[2048];
    int tid = threadIdx.x;
    double v0 = 0.0, v1 = 0.0;
    unsigned long long c0 = 0, c1 = 0;
#pragma unroll
    for (int r = 0; r < 8; ++r) {                  // sum replicas (L2-resident)
        v0 += (double)btot[r * K + 2 * tid];
        v1 += (double)btot[r * K + 2 * tid + 1];
        c0 += bev[r * K + 2 * tid];
        c1 += bev[r * K + 2 * tid + 1];
    }
    lds[tid] = v0 + v1; __syncthreads();
    for (int off = 1; off < 1024; off <<= 1) {
        double a = (tid >= off) ? lds[tid - off] : 0.0;
        __syncthreads();
        lds[tid] += a;
        __syncthreads();
    }
    double run = (tid == 0) ? 0.0 : lds[tid - 1];
    double r0 = run + v0;
    double r1 = r0 + v1;
    double dot = 0.0;
    if (c0) dot += (double)c0 * log(r0);
    if (c1) dot += (double)c1 * log(r1);
    __syncthreads();

    double foc = 0.0, reg = 0.0, seh = 0.0, nev = 0.0;
    if (tid < NB)  { foc = partW[tid * 2 + 0]; reg = partW[tid * 2 + 1]; }
    if (tid < NHB) { seh = partH[tid * 2 + 0]; nev = partH[tid * 2 + 1]; }

    lds[tid] = dot; lds[1024 + tid] = foc; __syncthreads();
    for (int s = 512; s > 0; s >>= 1) {
        if (tid < s) { lds[tid] += lds[tid + s]; lds[1024 + tid] += lds[1024 + tid + s]; }
        __syncthreads();
    }
    double dotT = lds[0], focT = lds[1024]; __syncthreads();
    lds[tid] = reg; lds[1024 + tid] = seh; __syncthreads();
    for (int s = 512; s > 0; s >>= 1) {
        if (tid < s) { lds[tid] += lds[tid + s]; lds[1024 + tid] += lds[1024 + tid + s]; }
        __syncthreads();
    }
    double regT = lds[0], sehT = lds[1024]; __syncthreads();
    lds[tid] = nev; __syncthreads();
    for (int s = 512; s > 0; s >>= 1) {
        if (tid < s) lds[tid] += lds[tid + s];
        __syncthreads();
    }
    if (tid == 0) {
        double neT = lds[0];
        double cox = sehT - dotT;                  // Σ_events (h - logS)
        double surv = -cox / (neT + 1e-8);
        double rec = focT / (double)n;
        double rg = 1e-4 * regT;
        double a = (double)lsv[0], b = (double)lrv[0], c = (double)lgv[0];
        double sp = exp(-a), rpv = exp(-b), gp = exp(-c);
        double total = sp * surv + rpv * rec + gp * rg + a + b + c;
        out[0] = (float)total;
        out[1] = (float)surv;
        out[2] = (float)rec;
        out[3] = (float)rg;
        out[4] = (float)sp;
        out[5] = (float)rpv;
    }
}

extern "C" void kernel_launch(void* const* d_in, const int* in_sizes, int n_in,
                              void* d_out, int out_size, void* d_ws, size_t ws_size,
                              hipStream_t stream) {
    const float* h   = (const float*)d_in[0];
    const float* rp  = (const float*)d_in[1];
    const float* tm  = (const float*)d_in[2];
    const int*   ev  = (const int*)d_in[3];
    const int*   rl  = (const int*)d_in[4];
    const float* pw  = (const float*)d_in[5];
    const float* pb  = (const float*)d_in[6];
    const float* lsv = (const float*)d_in[7];
    const float* lrv = (const float*)d_in[8];
    const float* lgv = (const float*)d_in[9];
    int n  = in_sizes[0];
    int nw = in_sizes[5];
    int nb = in_sizes[6];
    float* out = (float*)d_out;

    float*    btot  = (float*)d_ws;                // NREP*K floats
    unsigned* bev   = (unsigned*)(btot + NREP * K);// NREP*K uints
    double*   partW = (double*)(bev + NREP * K);   // NB*2 doubles
    double*   partH = partW + 2 * NB;              // NHB*2 doubles

    hipMemsetAsync(btot, 0, (size_t)NREP * K * 8, stream);   // btot + bev
    k1<<<NB, 1024, 0, stream>>>(tm, h, ev, n, rp, rl, pw, nw, pb, nb,
                                btot, bev, partW, partH);
    kTail<<<1, 1024, 0, stream>>>(btot, bev, partW, partH, lsv, lrv, lgv, n, out);
}

// Round 22
// 51.128 us; speedup vs baseline: 1.1969x; 1.0150x over previous
//
#include <hip/hip_runtime.h>
#include <math.h>

#define K 2048           // time buckets
#define NREP 8           // btot/bev replicas (atomic contention / 8)
#define NHB 256          // histogram-role blocks, 1024 thr
#define NWB 256          // focal-role blocks, 1024 thr
#define NB (NHB + NWB)
#define PS_H 6144        // pw float4s per hist block
#define PS_W 10240       // pw float4s per work block (256*(6144+10240) = nw/4)

// native clang vector types — __builtin_nontemporal_load requires these
typedef float f32x4 __attribute__((ext_vector_type(4)));
typedef int   i32x4 __attribute__((ext_vector_type(4)));

// non-temporal 16B loads: stream past L2/L3 line-fill (zero-reuse data)
__device__ __forceinline__ f32x4 nt4f(const float4* p) {
    return __builtin_nontemporal_load((const f32x4*)p);
}
__device__ __forceinline__ i32x4 nt4i(const int4* p) {
    return __builtin_nontemporal_load((const i32x4*)p);
}

// ---------------- k1: R19 structure + non-temporal stream loads --------------
__global__ __launch_bounds__(1024) void k1(
    const float* __restrict__ tm, const float* __restrict__ h,
    const int* __restrict__ ev, int n,
    const float* __restrict__ rp, const int* __restrict__ rl,
    const float* __restrict__ pw, int nw,
    const float* __restrict__ pb, int nb,
    float* __restrict__ btot, unsigned* __restrict__ bev,
    double* __restrict__ partW, double* __restrict__ partH) {
    __shared__ __align__(16) char smem[16384];
    float*    hist   = (float*)smem;              // [K]
    unsigned* histev = (unsigned*)(smem + 8192);  // [K]
    double*   lds    = (double*)smem;             // reused after flush
    int bid = blockIdx.x, tid = threadIdx.x;
    double foc = 0.0, reg = 0.0, seh = 0.0;
    int ne = 0;

    const float4* mypw;
    int mycnt;

    if (bid < NHB) {
        // ---- histogram role ----
        for (int j = tid; j < K; j += 1024) { hist[j] = 0.f; histev[j] = 0u; }
        __syncthreads();
        const float4* tm4 = (const float4*)tm + (long long)bid * 4096;
        const float4* h4  = (const float4*)h  + (long long)bid * 4096;
        const int4*   ev4 = (const int4*)ev  + (long long)bid * 4096;
#define HL(tc, hc, ec)                                                        \
        {                                                                     \
            unsigned b = (unsigned)((tc) * (float)K);                         \
            if (b > K - 1u) b = K - 1u;                                       \
            atomicAdd(&hist[b], __expf(hc));                                  \
            if (ec) { atomicAdd(&histev[b], 1u);                              \
                      seh += (double)(hc); ne += 1; }                         \
        }
        for (int i = tid; i < 4096; i += 2048) {   // 2 iters; 6 loads in flight
            f32x4 T0 = nt4f(tm4 + i),        H0 = nt4f(h4 + i);
            i32x4 E0 = nt4i(ev4 + i);
            f32x4 T1 = nt4f(tm4 + i + 1024), H1 = nt4f(h4 + i + 1024);
            i32x4 E1 = nt4i(ev4 + i + 1024);
            HL(T0[0], H0[0], E0[0]) HL(T0[1], H0[1], E0[1])
            HL(T0[2], H0[2], E0[2]) HL(T0[3], H0[3], E0[3])
            HL(T1[0], H1[0], E1[0]) HL(T1[1], H1[1], E1[1])
            HL(T1[2], H1[2], E1[2]) HL(T1[3], H1[3], E1[3])
        }
#undef HL
        __syncthreads();
        // ---- replicated + rotated flush ----
        {
            float*    myb  = btot + (size_t)(bid & (NREP - 1)) * K;
            unsigned* mybe = bev  + (size_t)(bid & (NREP - 1)) * K;
            int rot = (bid * 37) & (K - 1);
            for (int jj = tid; jj < K; jj += 1024) {
                int j = (jj + rot) & (K - 1);
                float v = hist[j];
                if (v != 0.f) atomicAdd(&myb[j], v);
                unsigned c = histev[j];
                if (c) atomicAdd(&mybe[j], c);
            }
        }
        mypw  = (const float4*)pw + (long long)bid * PS_H;
        mycnt = PS_H;
    } else {
        // ---- focal role ----
        int widx = bid - NHB;
        const float4* rp4 = (const float4*)rp + (long long)widx * 4096;
        const int4*   rl4 = (const int4*)rl + (long long)widx * 4096;
#define FOC(pc, lc)                                                           \
        {                                                                     \
            float pp = pc; float tt = (float)(lc);                            \
            float ce = fmaxf(pp, 0.f) - pp * tt                               \
                     + __logf(1.f + __expf(-fabsf(pp)));                      \
            float ptv = __expf(-ce); float om = 1.f - ptv;                    \
            foc += (double)((0.25f * tt + 0.75f * (1.f - tt)) * om * om * ce);\
        }
        for (int i = tid; i < 4096; i += 2048) {   // 2 iters; 4 loads in flight
            f32x4 P0 = nt4f(rp4 + i);
            i32x4 L0 = nt4i(rl4 + i);
            f32x4 P1 = nt4f(rp4 + i + 1024);
            i32x4 L1 = nt4i(rl4 + i + 1024);
            FOC(P0[0], L0[0]) FOC(P0[1], L0[1]) FOC(P0[2], L0[2]) FOC(P0[3], L0[3])
            FOC(P1[0], L1[0]) FOC(P1[1], L1[1]) FOC(P1[2], L1[2]) FOC(P1[3], L1[3])
        }
#undef FOC
        mypw  = (const float4*)pw + (long long)NHB * PS_H + (long long)widx * PS_W;
        mycnt = PS_W;
    }

    // ---- common: pw slice (non-temporal) ----
#define SQ4(V) {                                                              \
        float s_ = (V)[0] * (V)[0] + (V)[1] * (V)[1]                          \
                 + (V)[2] * (V)[2] + (V)[3] * (V)[3];                         \
        reg += (double)s_; }
#pragma unroll 2
    for (int i = tid; i < mycnt; i += 1024) {
        f32x4 v = nt4f(mypw + i);
        SQ4(v)
    }
    if (bid == NHB) {                              // pb: 1024 float4s, once
        int nb4 = nb >> 2;
        if (tid < nb4) {
            f32x4 v = nt4f((const float4*)pb + tid);
            SQ4(v)
        }
    }
#undef SQ4

    __syncthreads();                               // LDS hist no longer needed
    lds[tid] = foc; lds[1024 + tid] = reg; __syncthreads();
    for (int s = 512; s > 0; s >>= 1) {
        if (tid < s) { lds[tid] += lds[tid + s]; lds[1024 + tid] += lds[1024 + tid + s]; }
        __syncthreads();
    }
    if (tid == 0) { partW[bid * 2 + 0] = lds[0]; partW[bid * 2 + 1] = lds[1024]; }
    if (bid < NHB) {
        __syncthreads();
        lds[tid] = seh; lds[1024 + tid] = (double)ne; __syncthreads();
        for (int s = 512; s > 0; s >>= 1) {
            if (tid < s) { lds[tid] += lds[tid + s]; lds[1024 + tid] += lds[1024 + tid + s]; }
            __syncthreads();
        }
        if (tid == 0) { partH[bid * 2 + 0] = lds[0]; partH[bid * 2 + 1] = lds[1024]; }
    }
}

// ---------------- kTail: replica-sum + scan + dot + reduce + combine ---------
__global__ __launch_bounds__(1024) void kTail(
    const float* __restrict__ btot, const unsigned* __restrict__ bev,
    const double* __restrict__ partW, const double* __restrict__ partH,
    const float* __restrict__ lsv, const float* __restrict__ lrv,
    const float* __restrict__ lgv, int n, float* __restrict__ out) {
    __shared__ double lds[2048];
    int tid = threadIdx.x;
    double v0 = 0.0, v1 = 0.0;
    unsigned long long c0 = 0, c1 = 0;
#pragma unroll
    for (int r = 0; r < 8; ++r) {                  // sum replicas (L2-resident)
        v0 += (double)btot[r * K + 2 * tid];
        v1 += (double)btot[r * K + 2 * tid + 1];
        c0 += bev[r * K + 2 * tid];
        c1 += bev[r * K + 2 * tid + 1];
    }
    lds[tid] = v0 + v1; __syncthreads();
    for (int off = 1; off < 1024; off <<= 1) {
        double a = (tid >= off) ? lds[tid - off] : 0.0;
        __syncthreads();
        lds[tid] += a;
        __syncthreads();
    }
    double run = (tid == 0) ? 0.0 : lds[tid - 1];
    double r0 = run + v0;
    double r1 = r0 + v1;
    double dot = 0.0;
    if (c0) dot += (double)c0 * log(r0);
    if (c1) dot += (double)c1 * log(r1);
    __syncthreads();

    double foc = 0.0, reg = 0.0, seh = 0.0, nev = 0.0;
    if (tid < NB)  { foc = partW[tid * 2 + 0]; reg = partW[tid * 2 + 1]; }
    if (tid < NHB) { seh = partH[tid * 2 + 0]; nev = partH[tid * 2 + 1]; }

    lds[tid] = dot; lds[1024 + tid] = foc; __syncthreads();
    for (int s = 512; s > 0; s >>= 1) {
        if (tid < s) { lds[tid] += lds[tid + s]; lds[1024 + tid] += lds[1024 + tid + s]; }
        __syncthreads();
    }
    double dotT = lds[0], focT = lds[1024]; __syncthreads();
    lds[tid] = reg; lds[1024 + tid] = seh; __syncthreads();
    for (int s = 512; s > 0; s >>= 1) {
        if (tid < s) { lds[tid] += lds[tid + s]; lds[1024 + tid] += lds[1024 + tid + s]; }
        __syncthreads();
    }
    double regT = lds[0], sehT = lds[1024]; __syncthreads();
    lds[tid] = nev; __syncthreads();
    for (int s = 512; s > 0; s >>= 1) {
        if (tid < s) lds[tid] += lds[tid + s];
        __syncthreads();
    }
    if (tid == 0) {
        double neT = lds[0];
        double cox = sehT - dotT;                  // Σ_events (h - logS)
        double surv = -cox / (neT + 1e-8);
        double rec = focT / (double)n;
        double rg = 1e-4 * regT;
        double a = (double)lsv[0], b = (double)lrv[0], c = (double)lgv[0];
        double sp = exp(-a), rpv = exp(-b), gp = exp(-c);
        double total = sp * surv + rpv * rec + gp * rg + a + b + c;
        out[0] = (float)total;
        out[1] = (float)surv;
        out[2] = (float)rec;
        out[3] = (float)rg;
        out[4] = (float)sp;
        out[5] = (float)rpv;
    }
}

extern "C" void kernel_launch(void* const* d_in, const int* in_sizes, int n_in,
                              void* d_out, int out_size, void* d_ws, size_t ws_size,
                              hipStream_t stream) {
    const float* h   = (const float*)d_in[0];
    const float* rp  = (const float*)d_in[1];
    const float* tm  = (const float*)d_in[2];
    const int*   ev  = (const int*)d_in[3];
    const int*   rl  = (const int*)d_in[4];
    const float* pw  = (const float*)d_in[5];
    const float* pb  = (const float*)d_in[6];
    const float* lsv = (const float*)d_in[7];
    const float* lrv = (const float*)d_in[8];
    const float* lgv = (const float*)d_in[9];
    int n  = in_sizes[0];
    int nw = in_sizes[5];
    int nb = in_sizes[6];
    float* out = (float*)d_out;

    float*    btot  = (float*)d_ws;                // NREP*K floats
    unsigned* bev   = (unsigned*)(btot + NREP * K);// NREP*K uints
    double*   partW = (double*)(bev + NREP * K);   // NB*2 doubles
    double*   partH = partW + 2 * NB;              // NHB*2 doubles

    hipMemsetAsync(btot, 0, (size_t)NREP * K * 8, stream);   // btot + bev
    k1<<<NB, 1024, 0, stream>>>(tm, h, ev, n, rp, rl, pw, nw, pb, nb,
                                btot, bev, partW, partH);
    kTail<<<1, 1024, 0, stream>>>(btot, bev, partW, partH, lsv, lrv, lgv, n, out);
}